// Round 14
// baseline (130.971 us; speedup 1.0000x reference)
//
#include <hip/hip_runtime.h>
#include <hip/hip_bf16.h>
#include <cstdint>
#include <cstddef>

// GAT layer forward for MI355X (gfx950).
// N=50000, E=1.6M, F=256, H=64 (derived at runtime).
// Outputs (concat in d_out): out [N,H] f32, alpha [E] f32.

constexpr int FDIM = 256;
constexpr int HDIM = 64;
constexpr float LEAKY = 0.05f;

typedef __attribute__((ext_vector_type(8))) short short8v;   // 8 bf16 = 4 VGPR
typedef __attribute__((ext_vector_type(4))) float f32x4;

__device__ __forceinline__ short bfs(float f) {
  return (short)__builtin_bit_cast(unsigned short, __float2bfloat16(f));
}
__device__ __forceinline__ short8v cvt8(float4 lo, float4 hi) {
  short8v r;
  r[0] = bfs(lo.x); r[1] = bfs(lo.y); r[2] = bfs(lo.z); r[3] = bfs(lo.w);
  r[4] = bfs(hi.x); r[5] = bfs(hi.y); r[6] = bfs(hi.z); r[7] = bfs(hi.w);
  return r;
}
__device__ __forceinline__ float blo(unsigned int w) { return __uint_as_float(w << 16); }
__device__ __forceinline__ float bhi(unsigned int w) { return __uint_as_float(w & 0xffff0000u); }

// ---------------------------------------------------------------------------
// K0: pack fc_w (f32 [64][256]) into bf16 MFMA B-fragments.
// ---------------------------------------------------------------------------
__global__ __launch_bounds__(256) void k_wt(
    const float* __restrict__ fcw, short* __restrict__ wb)
{
  const int t = blockIdx.x * 256 + threadIdx.x;   // 0 .. 2047
  const int f = t >> 6;
  const int lane = t & 63;
  const int ks = f >> 2, cb = f & 3;
  const int col = cb * 16 + (lane & 15);
  const int kb = ks * 32 + (lane >> 4) * 8;
  short8v v;
  #pragma unroll
  for (int j = 0; j < 8; ++j) v[j] = bfs(fcw[col * FDIM + kb + j]);
  reinterpret_cast<short8v*>(wb)[t] = v;
}

// ---------------------------------------------------------------------------
// K1: MFMA GEMM z = x @ fc_w^T (bf16 in, f32 acc), fused s1/s2, z out bf16.
// C/D layout (verified): col = lane&15, row = (lane>>4)*4 + reg.
// ---------------------------------------------------------------------------
__global__ __launch_bounds__(256) void k_fcm(
    const float* __restrict__ x, const short* __restrict__ wb,
    const float* __restrict__ aw,
    unsigned short* __restrict__ zb, float* __restrict__ s1,
    float* __restrict__ s2, int N)
{
  __shared__ __align__(16) unsigned short zt[128 * 72];   // 18.4 KB transpose buf

  const int tid = threadIdx.x;
  const int lane = tid & 63;
  const int wave = tid >> 6;
  const int n0 = blockIdx.x * 128;
  const int rb = n0 + wave * 32;
  const int l4 = lane >> 4;      // k-group / row-group
  const int lm = lane & 15;      // A-row / B-col within tile

  f32x4 acc[2][4] = {};

  const int r0c = min(rb + lm, N - 1);
  const int r1c = min(rb + 16 + lm, N - 1);
  const float* xp0 = x + (size_t)r0c * FDIM + l4 * 8;
  const float* xp1 = x + (size_t)r1c * FDIM + l4 * 8;
  const short8v* wbv = reinterpret_cast<const short8v*>(wb);

  #pragma unroll
  for (int ks = 0; ks < 8; ++ks) {
    const float4 a0l = *reinterpret_cast<const float4*>(xp0 + ks * 32);
    const float4 a0h = *reinterpret_cast<const float4*>(xp0 + ks * 32 + 4);
    const float4 a1l = *reinterpret_cast<const float4*>(xp1 + ks * 32);
    const float4 a1h = *reinterpret_cast<const float4*>(xp1 + ks * 32 + 4);
    const short8v fa0 = cvt8(a0l, a0h);
    const short8v fa1 = cvt8(a1l, a1h);
    #pragma unroll
    for (int cb = 0; cb < 4; ++cb) {
      const short8v fb = wbv[(ks * 4 + cb) * 64 + lane];
      acc[0][cb] = __builtin_amdgcn_mfma_f32_16x16x32_bf16(fa0, fb, acc[0][cb], 0, 0, 0);
      acc[1][cb] = __builtin_amdgcn_mfma_f32_16x16x32_bf16(fa1, fb, acc[1][cb], 0, 0, 0);
    }
  }

  // fused s1/s2
  float aw1l[4], aw2l[4];
  #pragma unroll
  for (int cb = 0; cb < 4; ++cb) {
    aw1l[cb] = aw[cb * 16 + lm];
    aw2l[cb] = aw[HDIM + cb * 16 + lm];
  }
  #pragma unroll
  for (int mb = 0; mb < 2; ++mb) {
    const int rloc = rb + mb * 16 + l4 * 4;
    #pragma unroll
    for (int reg = 0; reg < 4; ++reg) {
      float t1 = 0.f, t2 = 0.f;
      #pragma unroll
      for (int cb = 0; cb < 4; ++cb) {
        t1 = fmaf(acc[mb][cb][reg], aw1l[cb], t1);
        t2 = fmaf(acc[mb][cb][reg], aw2l[cb], t2);
      }
      #pragma unroll
      for (int off = 1; off < 16; off <<= 1) {
        t1 += __shfl_xor(t1, off, 64);
        t2 += __shfl_xor(t2, off, 64);
      }
      if (lm == reg && rloc + reg < N) {
        s1[rloc + reg] = t1;
        s2[rloc + reg] = t2;
      }
    }
  }

  // z -> bf16 via LDS transpose, then coalesced stores (64B per thread)
  #pragma unroll
  for (int mb = 0; mb < 2; ++mb)
    #pragma unroll
    for (int cb = 0; cb < 4; ++cb)
      #pragma unroll
      for (int reg = 0; reg < 4; ++reg) {
        const int rl = wave * 32 + mb * 16 + l4 * 4 + reg;
        zt[rl * 72 + cb * 16 + lm] =
            (unsigned short)__builtin_bit_cast(unsigned short,
                __float2bfloat16(acc[mb][cb][reg]));
      }
  __syncthreads();
  const int row = tid >> 1, hf = tid & 1;   // 32 u16 = 64 B = 4 x uint4 each
  const int n = n0 + row;
  if (n < N) {
    const uint4* s = reinterpret_cast<const uint4*>(&zt[row * 72 + hf * 32]);
    uint4 v0 = s[0], v1 = s[1], v2 = s[2], v3 = s[3];
    uint4* d = reinterpret_cast<uint4*>(zb + (size_t)n * HDIM + hf * 32);
    d[0] = v0; d[1] = v1; d[2] = v2; d[3] = v3;
  }
}

// ---------------------------------------------------------------------------
// K2a: per-chunk bucket histogram (bucket = src >> 8) + chunk-local exclusive
// base. hist bucket-major hist[b*nCh+c]; lbs chunk-major lbs[c*256+b].
// ---------------------------------------------------------------------------
__global__ __launch_bounds__(1024) void k_b1(
    const int* __restrict__ src, unsigned int* __restrict__ hist,
    unsigned int* __restrict__ lbs, int E, int nB, int nCh, int chunkLg)
{
  __shared__ unsigned int lh[256];
  __shared__ unsigned int part[256];
  const int tid = threadIdx.x;
  if (tid < 256) lh[tid] = 0;
  __syncthreads();
  const int e0 = blockIdx.x << chunkLg;
  const int e1 = min(e0 + (1 << chunkLg), E);
  for (int e = e0 + tid; e < e1; e += 1024)
    atomicAdd(&lh[src[e] >> 8], 1u);
  __syncthreads();
  if (tid < 256) part[tid] = lh[tid];
  __syncthreads();
  for (int off = 1; off < 256; off <<= 1) {
    unsigned int t = (tid < 256 && tid >= off) ? part[tid - off] : 0;
    __syncthreads();
    if (tid < 256) part[tid] += t;
    __syncthreads();
  }
  if (tid < nB) {
    hist[(size_t)tid * nCh + blockIdx.x] = lh[tid];
    lbs[(size_t)blockIdx.x * 256 + tid] = part[tid] - lh[tid];
  }
}

// ---------------------------------------------------------------------------
// K2b: ONE block: per-bucket exclusive scan over chunks (16 waves stride the
// bucket rows), then in-block exclusive scan of bucket totals -> bucket_base.
// ---------------------------------------------------------------------------
__global__ __launch_bounds__(1024) void k_bscan(
    unsigned int* __restrict__ hist, int* __restrict__ bucket_base,
    int nB, int nCh, int E)
{
  __shared__ unsigned int tot[256];
  __shared__ unsigned int part[256];
  const int wave = threadIdx.x >> 6;
  const int lane = threadIdx.x & 63;
  const int t = threadIdx.x;
  if (t < 256) tot[t] = 0;
  __syncthreads();

  for (int b = wave; b < nB; b += 16) {
    unsigned int* row = hist + (size_t)b * nCh;
    unsigned int running = 0;
    for (int j = 0; j < nCh; j += 64) {
      const int c = j + lane;
      unsigned int v = (c < nCh) ? row[c] : 0;
      unsigned int s = v;
      #pragma unroll
      for (int off = 1; off < 64; off <<= 1) {
        unsigned int u = __shfl_up(s, off, 64);
        if (lane >= off) s += u;
      }
      if (c < nCh) row[c] = running + s - v;     // exclusive within bucket
      running += __shfl(s, 63, 64);
    }
    if (lane == 0) tot[b] = running;
  }
  __syncthreads();

  const unsigned int v = (t < 256) ? tot[t] : 0;
  if (t < 256) part[t] = v;
  __syncthreads();
  for (int off = 1; off < 256; off <<= 1) {
    unsigned int u = (t < 256 && t >= off) ? part[t - off] : 0;
    __syncthreads();
    if (t < 256) part[t] += u;
    __syncthreads();
  }
  if (t < nB) bucket_base[t] = (int)(part[t] - v);
  if (t == 0) bucket_base[nB] = E;
}

// ---------------------------------------------------------------------------
// K2d: bucket scatter with LDS staging -> COALESCED global dumps.
// Pack val = (src<<16)|dst. bucket(val) = val >> 24. Bases precomputed by b1.
// ---------------------------------------------------------------------------
__global__ __launch_bounds__(1024) void k_b2(
    const int* __restrict__ src, const int* __restrict__ dst,
    const unsigned int* __restrict__ hist, const unsigned int* __restrict__ lbs,
    const int* __restrict__ bucket_base,
    unsigned int* __restrict__ bucketed, int E, int nB, int nCh, int chunkLg)
{
  __shared__ unsigned int staged[8192];    // 32 KB (chunkLg=13)
  __shared__ unsigned int gbase[256];
  __shared__ unsigned int lbase[256];
  __shared__ unsigned int lcur[256];

  const int tid = threadIdx.x;
  const int c = blockIdx.x;
  if (tid < nB) {
    gbase[tid] = (unsigned int)bucket_base[tid] + hist[(size_t)tid * nCh + c];
    const unsigned int lb = lbs[(size_t)c * 256 + tid];
    lbase[tid] = lb;
    lcur[tid] = lb;
  }
  __syncthreads();

  const int e0 = c << chunkLg;
  const int e1 = min(e0 + (1 << chunkLg), E);
  const int csize = e1 - e0;

  for (int e = e0 + tid; e < e1; e += 1024) {
    const unsigned int s = (unsigned int)src[e];
    const unsigned int pos = atomicAdd(&lcur[s >> 8], 1u);
    staged[pos] = (s << 16) | (unsigned int)dst[e];
  }
  __syncthreads();

  // linear dump: consecutive i within a bucket run -> consecutive gpos
  for (int i = tid; i < csize; i += 1024) {
    const unsigned int v = staged[i];
    const unsigned int b = v >> 24;
    bucketed[gbase[b] + ((unsigned int)i - lbase[b])] = v;
  }
}

// ---------------------------------------------------------------------------
// K2e: one block per bucket: node hist + scan -> rowptr; scatter dst into
// LDS staging; contiguous coalesced dump into csr_dst.
// ---------------------------------------------------------------------------
__global__ __launch_bounds__(1024) void k_b3(
    const unsigned int* __restrict__ bucketed, const int* __restrict__ bucket_base,
    int* __restrict__ rowptr, unsigned short* __restrict__ csr_dst,
    int nB, int N, int E)
{
  __shared__ unsigned short staged[16384];   // 32 KB
  __shared__ unsigned int lh[256];
  __shared__ unsigned int part[256];
  __shared__ unsigned int cur[256];

  const int b = blockIdx.x;
  const int tid = threadIdx.x;
  const int seg0 = bucket_base[b];
  const int seg1 = bucket_base[b + 1];
  const int len = seg1 - seg0;
  if (tid < 256) lh[tid] = 0;
  __syncthreads();

  for (int j = seg0 + tid; j < seg1; j += 1024)
    atomicAdd(&lh[(bucketed[j] >> 16) & 0xFFu], 1u);
  __syncthreads();

  if (tid < 256) part[tid] = lh[tid];
  __syncthreads();
  for (int off = 1; off < 256; off <<= 1) {
    unsigned int t = (tid < 256 && tid >= off) ? part[tid - off] : 0;
    __syncthreads();
    if (tid < 256) part[tid] += t;
    __syncthreads();
  }
  if (tid < 256) {
    const unsigned int base = part[tid] - lh[tid];   // local exclusive
    cur[tid] = base;
    const int n = b * 256 + tid;
    if (n < N) rowptr[n] = seg0 + (int)base;
  }
  if (b == nB - 1 && tid == 0) rowptr[N] = E;
  __syncthreads();

  if (len <= 16384) {
    for (int j = seg0 + tid; j < seg1; j += 1024) {
      const unsigned int v = bucketed[j];
      const unsigned int pos = atomicAdd(&cur[(v >> 16) & 0xFFu], 1u);
      staged[pos] = (unsigned short)(v & 0xFFFFu);
    }
    __syncthreads();
    for (int i = tid; i < len; i += 1024)     // contiguous coalesced dump
      csr_dst[seg0 + i] = staged[i];
  } else {
    for (int j = seg0 + tid; j < seg1; j += 1024) {   // fallback
      const unsigned int v = bucketed[j];
      const unsigned int pos = atomicAdd(&cur[(v >> 16) & 0xFFu], 1u);
      csr_dst[seg0 + pos] = (unsigned short)(v & 0xFFFFu);
    }
  }
}

// ---------------------------------------------------------------------------
// K5: node-centric accumulate; wave/node; 4 edges per gather iteration.
// Lane quarter q = edge slot, lane&15 = 4-feature group (uint2 = 4 bf16).
// h/dl broadcast through LDS; manual 4x batching -> 16 edges in flight.
// ---------------------------------------------------------------------------
__global__ __launch_bounds__(256) void k_node(
    const unsigned short* __restrict__ csr_dst, const int* __restrict__ rowptr,
    const float* __restrict__ s1, const float* __restrict__ s2,
    const float* __restrict__ ab, const unsigned short* __restrict__ zb,
    float* __restrict__ out, float* __restrict__ rinv, int N)
{
  __shared__ float hbuf[4][64];
  __shared__ int   dbuf[4][64];

  const int wave = threadIdx.x >> 6;
  const int node = blockIdx.x * 4 + wave;
  const int lane = threadIdx.x & 63;
  if (node >= N) return;
  const int r0 = rowptr[node];
  const int r1 = rowptr[node + 1];
  const int q  = lane >> 4;          // edge slot within quad
  const int f4 = (lane & 15) << 2;   // 4-feature base
  if (r1 == r0) {                    // degree-0: reference yields zeros
    out[(size_t)node * HDIM + lane] = 0.f;
    if (lane == 0) rinv[node] = 0.f;
    return;
  }
  const float s1n = s1[node];
  const float b = ab[0];
  float a0 = 0.f, a1 = 0.f, a2 = 0.f, a3 = 0.f, hs = 0.f;
  float* hb = hbuf[wave];
  int*   db = dbuf[wave];

  for (int base = r0; base < r1; base += 64) {
    const int j = base + lane;
    float h = 0.f;
    int dl = 0;
    if (j < r1) {
      dl = (int)csr_dst[j];                  // coalesced u16
      float v = s1n + s2[dl] + b;            // gathered 4B (L2-resident)
      v = v > 0.f ? v : LEAKY * v;
      h = __expf(v);
    }
    hs += h;
    hb[lane] = h;                            // wave-private LDS, no barrier
    db[lane] = dl;
    const int cnt = min(64, r1 - base);
    const int quads = (cnt + 3) >> 2;
    int t = 0;
    for (; t + 4 <= quads; t += 4) {
      const int i0 = 4 * t + q;
      const float h0 = hb[i0],     h1 = hb[i0 + 4];
      const float h2 = hb[i0 + 8], h3 = hb[i0 + 12];
      const int   d0 = db[i0],     d1 = db[i0 + 4];
      const int   d2 = db[i0 + 8], d3 = db[i0 + 12];
      const uint2 w0 = *reinterpret_cast<const uint2*>(zb + (size_t)d0 * HDIM + f4);
      const uint2 w1 = *reinterpret_cast<const uint2*>(zb + (size_t)d1 * HDIM + f4);
      const uint2 w2 = *reinterpret_cast<const uint2*>(zb + (size_t)d2 * HDIM + f4);
      const uint2 w3 = *reinterpret_cast<const uint2*>(zb + (size_t)d3 * HDIM + f4);
      a0 = fmaf(h0, blo(w0.x), a0); a1 = fmaf(h0, bhi(w0.x), a1);
      a2 = fmaf(h0, blo(w0.y), a2); a3 = fmaf(h0, bhi(w0.y), a3);
      a0 = fmaf(h1, blo(w1.x), a0); a1 = fmaf(h1, bhi(w1.x), a1);
      a2 = fmaf(h1, blo(w1.y), a2); a3 = fmaf(h1, bhi(w1.y), a3);
      a0 = fmaf(h2, blo(w2.x), a0); a1 = fmaf(h2, bhi(w2.x), a1);
      a2 = fmaf(h2, blo(w2.y), a2); a3 = fmaf(h2, bhi(w2.y), a3);
      a0 = fmaf(h3, blo(w3.x), a0); a1 = fmaf(h3, bhi(w3.x), a1);
      a2 = fmaf(h3, blo(w3.y), a2); a3 = fmaf(h3, bhi(w3.y), a3);
    }
    for (; t + 2 <= quads; t += 2) {
      const int i0 = 4 * t + q, i1 = i0 + 4;
      const float h0 = hb[i0], h1 = hb[i1];
      const int   d0 = db[i0], d1 = db[i1];
      const uint2 w0 = *reinterpret_cast<const uint2*>(zb + (size_t)d0 * HDIM + f4);
      const uint2 w1 = *reinterpret_cast<const uint2*>(zb + (size_t)d1 * HDIM + f4);
      a0 = fmaf(h0, blo(w0.x), a0); a1 = fmaf(h0, bhi(w0.x), a1);
      a2 = fmaf(h0, blo(w0.y), a2); a3 = fmaf(h0, bhi(w0.y), a3);
      a0 = fmaf(h1, blo(w1.x), a0); a1 = fmaf(h1, bhi(w1.x), a1);
      a2 = fmaf(h1, blo(w1.y), a2); a3 = fmaf(h1, bhi(w1.y), a3);
    }
    for (; t < quads; ++t) {
      const int i0 = 4 * t + q;
      const float h0 = hb[i0];
      const int   d0 = db[i0];
      const uint2 w0 = *reinterpret_cast<const uint2*>(zb + (size_t)d0 * HDIM + f4);
      a0 = fmaf(h0, blo(w0.x), a0); a1 = fmaf(h0, bhi(w0.x), a1);
      a2 = fmaf(h0, blo(w0.y), a2); a3 = fmaf(h0, bhi(w0.y), a3);
    }
  }
  #pragma unroll
  for (int off = 32; off > 0; off >>= 1) hs += __shfl_xor(hs, off, 64);
  // combine 4 edge-slot quarters (same feature group at lane^16, lane^32)
  a0 += __shfl_xor(a0, 16, 64); a1 += __shfl_xor(a1, 16, 64);
  a2 += __shfl_xor(a2, 16, 64); a3 += __shfl_xor(a3, 16, 64);
  a0 += __shfl_xor(a0, 32, 64); a1 += __shfl_xor(a1, 32, 64);
  a2 += __shfl_xor(a2, 32, 64); a3 += __shfl_xor(a3, 32, 64);
  const float inv = 1.0f / hs;
  if (lane < 16) {
    float4 o = {a0 * inv, a1 * inv, a2 * inv, a3 * inv};
    *reinterpret_cast<float4*>(out + (size_t)node * HDIM + f4) = o;
    if (lane == 0) rinv[node] = inv;
  }
}

// ---------------------------------------------------------------------------
// K6: alpha in edge order; 4 edges per thread (int4/float4).
// ---------------------------------------------------------------------------
__global__ __launch_bounds__(256) void k_alpha(
    const int* __restrict__ src, const int* __restrict__ dst,
    const float* __restrict__ s1, const float* __restrict__ s2,
    const float* __restrict__ ab, const float* __restrict__ rinv,
    float* __restrict__ alpha, int E)
{
  const int e = (blockIdx.x * blockDim.x + threadIdx.x) * 4;
  if (e >= E) return;
  const float bb = ab[0];
  if (e + 3 < E) {
    const int4 sv = *reinterpret_cast<const int4*>(src + e);
    const int4 dv = *reinterpret_cast<const int4*>(dst + e);
    float v0 = s1[sv.x] + s2[dv.x] + bb;
    float v1 = s1[sv.y] + s2[dv.y] + bb;
    float v2 = s1[sv.z] + s2[dv.z] + bb;
    float v3 = s1[sv.w] + s2[dv.w] + bb;
    v0 = v0 > 0.f ? v0 : LEAKY * v0;
    v1 = v1 > 0.f ? v1 : LEAKY * v1;
    v2 = v2 > 0.f ? v2 : LEAKY * v2;
    v3 = v3 > 0.f ? v3 : LEAKY * v3;
    float4 o = {__expf(v0) * rinv[sv.x], __expf(v1) * rinv[sv.y],
                __expf(v2) * rinv[sv.z], __expf(v3) * rinv[sv.w]};
    *reinterpret_cast<float4*>(alpha + e) = o;
  } else {
    for (int k = e; k < E; ++k) {
      const int s = src[k];
      float v = s1[s] + s2[dst[k]] + bb;
      v = v > 0.f ? v : LEAKY * v;
      alpha[k] = __expf(v) * rinv[s];
    }
  }
}

extern "C" void kernel_launch(void* const* d_in, const int* in_sizes, int n_in,
                              void* d_out, int out_size, void* d_ws, size_t ws_size,
                              hipStream_t stream) {
  const int E  = in_sizes[1] / 2;
  const int H2 = in_sizes[3];            // 2*H = 128
  const int Hh = H2 / 2;                 // 64
  const int Ff = in_sizes[2] / Hh;       // 256
  const int N  = in_sizes[0] / Ff;       // 50000

  const float* x   = (const float*)d_in[0];
  const int*   ei  = (const int*)d_in[1];
  const float* fcw = (const float*)d_in[2];
  const float* aw  = (const float*)d_in[3];
  const float* ab  = (const float*)d_in[4];
  const int* src = ei;
  const int* dst = ei + E;

  float* out   = (float*)d_out;
  float* alpha = out + (size_t)N * HDIM;

  const int nB = (N + 255) >> 8;                      // node buckets (<=256)
  int chunkLg = 13;                                   // keep nCh <= 256
  while (((E + (1 << chunkLg) - 1) >> chunkLg) > 256) ++chunkLg;
  const int nCh = (E + (1 << chunkLg) - 1) >> chunkLg;

  // workspace layout:
  // zb u16[N*64] | s1 f32[N] | s2 f32[N] | rinv f32[N] | wb s16[16384]
  // | rowptr i32[N+1] | bucket_base i32[nB+2] | bucketed u32[E]
  // | hist u32[nB*nCh] | lbs u32[nCh*256] | csr_dst u16[E]
  unsigned short* zb = (unsigned short*)d_ws;
  float* s1   = (float*)(zb + (size_t)N * HDIM);
  float* s2   = s1 + N;
  float* rinv = s2 + N;
  short* wb   = (short*)(rinv + N);
  int* rowptr = (int*)(wb + 8 * 4 * 64 * 8);
  int* bucket_base = rowptr + (N + 1);
  unsigned int* bucketed = (unsigned int*)(bucket_base + (nB + 2));
  unsigned int* hist = bucketed + E;
  unsigned int* lbs = hist + (size_t)nB * nCh;
  unsigned short* csr_dst = (unsigned short*)(lbs + (size_t)nCh * 256);

  k_wt<<<8, 256, 0, stream>>>(fcw, wb);
  k_fcm<<<(N + 127) / 128, 256, 0, stream>>>(x, wb, aw, zb, s1, s2, N);

  k_b1<<<nCh, 1024, 0, stream>>>(src, hist, lbs, E, nB, nCh, chunkLg);
  k_bscan<<<1, 1024, 0, stream>>>(hist, bucket_base, nB, nCh, E);
  k_b2<<<nCh, 1024, 0, stream>>>(src, dst, hist, lbs, bucket_base, bucketed,
                                 E, nB, nCh, chunkLg);
  k_b3<<<nB, 1024, 0, stream>>>(bucketed, bucket_base, rowptr, csr_dst, nB, N, E);

  k_node<<<(N + 3) / 4, 256, 0, stream>>>(
      csr_dst, rowptr, s1, s2, ab, zb, out, rinv, N);

  const int eb = (E + 1023) / 1024;
  k_alpha<<<eb, 256, 0, stream>>>(src, dst, s1, s2, ab, rinv, alpha, E);
}

// Round 15
// 103.927 us; speedup vs baseline: 1.2602x; 1.2602x over previous
//
#include <hip/hip_runtime.h>
#include <hip/hip_bf16.h>
#include <cstdint>
#include <cstddef>

// GAT layer forward for MI355X (gfx950).
// N=50000, E=1.6M, F=256, H=64 (derived at runtime).
// Outputs (concat in d_out): out [N,H] f32, alpha [E] f32.
// Best-measured configuration (106.95 us): parallel k_bsum + tiny k_bscan2,
// pair-gather k_node with LDS broadcast and 4x manual batching.

constexpr int FDIM = 256;
constexpr int HDIM = 64;
constexpr float LEAKY = 0.05f;

typedef __attribute__((ext_vector_type(8))) short short8v;   // 8 bf16 = 4 VGPR
typedef __attribute__((ext_vector_type(4))) float f32x4;

__device__ __forceinline__ short bfs(float f) {
  return (short)__builtin_bit_cast(unsigned short, __float2bfloat16(f));
}
__device__ __forceinline__ short8v cvt8(float4 lo, float4 hi) {
  short8v r;
  r[0] = bfs(lo.x); r[1] = bfs(lo.y); r[2] = bfs(lo.z); r[3] = bfs(lo.w);
  r[4] = bfs(hi.x); r[5] = bfs(hi.y); r[6] = bfs(hi.z); r[7] = bfs(hi.w);
  return r;
}

// ---------------------------------------------------------------------------
// K0: pack fc_w (f32 [64][256]) into bf16 MFMA B-fragments.
// ---------------------------------------------------------------------------
__global__ __launch_bounds__(256) void k_wt(
    const float* __restrict__ fcw, short* __restrict__ wb)
{
  const int t = blockIdx.x * 256 + threadIdx.x;   // 0 .. 2047
  const int f = t >> 6;
  const int lane = t & 63;
  const int ks = f >> 2, cb = f & 3;
  const int col = cb * 16 + (lane & 15);
  const int kb = ks * 32 + (lane >> 4) * 8;
  short8v v;
  #pragma unroll
  for (int j = 0; j < 8; ++j) v[j] = bfs(fcw[col * FDIM + kb + j]);
  reinterpret_cast<short8v*>(wb)[t] = v;
}

// ---------------------------------------------------------------------------
// K1: MFMA GEMM z = x @ fc_w^T (bf16 in, f32 acc), fused s1/s2, z out bf16.
// C/D layout (verified): col = lane&15, row = (lane>>4)*4 + reg.
// ---------------------------------------------------------------------------
__global__ __launch_bounds__(256) void k_fcm(
    const float* __restrict__ x, const short* __restrict__ wb,
    const float* __restrict__ aw,
    unsigned short* __restrict__ zb, float* __restrict__ s1,
    float* __restrict__ s2, int N)
{
  __shared__ __align__(16) unsigned short zt[128 * 72];   // 18.4 KB transpose buf

  const int tid = threadIdx.x;
  const int lane = tid & 63;
  const int wave = tid >> 6;
  const int n0 = blockIdx.x * 128;
  const int rb = n0 + wave * 32;
  const int l4 = lane >> 4;      // k-group / row-group
  const int lm = lane & 15;      // A-row / B-col within tile

  f32x4 acc[2][4] = {};

  const int r0c = min(rb + lm, N - 1);
  const int r1c = min(rb + 16 + lm, N - 1);
  const float* xp0 = x + (size_t)r0c * FDIM + l4 * 8;
  const float* xp1 = x + (size_t)r1c * FDIM + l4 * 8;
  const short8v* wbv = reinterpret_cast<const short8v*>(wb);

  #pragma unroll
  for (int ks = 0; ks < 8; ++ks) {
    const float4 a0l = *reinterpret_cast<const float4*>(xp0 + ks * 32);
    const float4 a0h = *reinterpret_cast<const float4*>(xp0 + ks * 32 + 4);
    const float4 a1l = *reinterpret_cast<const float4*>(xp1 + ks * 32);
    const float4 a1h = *reinterpret_cast<const float4*>(xp1 + ks * 32 + 4);
    const short8v fa0 = cvt8(a0l, a0h);
    const short8v fa1 = cvt8(a1l, a1h);
    #pragma unroll
    for (int cb = 0; cb < 4; ++cb) {
      const short8v fb = wbv[(ks * 4 + cb) * 64 + lane];
      acc[0][cb] = __builtin_amdgcn_mfma_f32_16x16x32_bf16(fa0, fb, acc[0][cb], 0, 0, 0);
      acc[1][cb] = __builtin_amdgcn_mfma_f32_16x16x32_bf16(fa1, fb, acc[1][cb], 0, 0, 0);
    }
  }

  // fused s1/s2
  float aw1l[4], aw2l[4];
  #pragma unroll
  for (int cb = 0; cb < 4; ++cb) {
    aw1l[cb] = aw[cb * 16 + lm];
    aw2l[cb] = aw[HDIM + cb * 16 + lm];
  }
  #pragma unroll
  for (int mb = 0; mb < 2; ++mb) {
    const int rloc = rb + mb * 16 + l4 * 4;
    #pragma unroll
    for (int reg = 0; reg < 4; ++reg) {
      float t1 = 0.f, t2 = 0.f;
      #pragma unroll
      for (int cb = 0; cb < 4; ++cb) {
        t1 = fmaf(acc[mb][cb][reg], aw1l[cb], t1);
        t2 = fmaf(acc[mb][cb][reg], aw2l[cb], t2);
      }
      #pragma unroll
      for (int off = 1; off < 16; off <<= 1) {
        t1 += __shfl_xor(t1, off, 64);
        t2 += __shfl_xor(t2, off, 64);
      }
      if (lm == reg && rloc + reg < N) {
        s1[rloc + reg] = t1;
        s2[rloc + reg] = t2;
      }
    }
  }

  // z -> bf16 via LDS transpose, then coalesced stores (64B per thread)
  #pragma unroll
  for (int mb = 0; mb < 2; ++mb)
    #pragma unroll
    for (int cb = 0; cb < 4; ++cb)
      #pragma unroll
      for (int reg = 0; reg < 4; ++reg) {
        const int rl = wave * 32 + mb * 16 + l4 * 4 + reg;
        zt[rl * 72 + cb * 16 + lm] =
            (unsigned short)__builtin_bit_cast(unsigned short,
                __float2bfloat16(acc[mb][cb][reg]));
      }
  __syncthreads();
  const int row = tid >> 1, hf = tid & 1;   // 32 u16 = 64 B = 4 x uint4 each
  const int n = n0 + row;
  if (n < N) {
    const uint4* s = reinterpret_cast<const uint4*>(&zt[row * 72 + hf * 32]);
    uint4 v0 = s[0], v1 = s[1], v2 = s[2], v3 = s[3];
    uint4* d = reinterpret_cast<uint4*>(zb + (size_t)n * HDIM + hf * 32);
    d[0] = v0; d[1] = v1; d[2] = v2; d[3] = v3;
  }
}

// ---------------------------------------------------------------------------
// K2a: per-chunk bucket histogram (bucket = src >> 8). hist is BUCKET-major:
// hist[b * nCh + c].
// ---------------------------------------------------------------------------
__global__ __launch_bounds__(1024) void k_b1(
    const int* __restrict__ src, unsigned int* __restrict__ hist,
    int E, int nB, int nCh, int chunkLg)
{
  __shared__ unsigned int lh[256];
  const int tid = threadIdx.x;
  if (tid < 256) lh[tid] = 0;
  __syncthreads();
  const int e0 = blockIdx.x << chunkLg;
  const int e1 = min(e0 + (1 << chunkLg), E);
  for (int e = e0 + tid; e < e1; e += 1024)
    atomicAdd(&lh[src[e] >> 8], 1u);
  __syncthreads();
  if (tid < nB) hist[(size_t)tid * nCh + blockIdx.x] = lh[tid];
}

// ---------------------------------------------------------------------------
// K2b: per-bucket exclusive scan over chunks (one WAVE per bucket, contiguous
// coalesced row). In-place; bucket total -> tot[b].
// ---------------------------------------------------------------------------
__global__ __launch_bounds__(256) void k_bsum(
    unsigned int* __restrict__ hist, unsigned int* __restrict__ tot,
    int nB, int nCh)
{
  const int b = blockIdx.x * 4 + (threadIdx.x >> 6);
  const int lane = threadIdx.x & 63;
  if (b >= nB) return;
  unsigned int* row = hist + (size_t)b * nCh;
  unsigned int running = 0;
  for (int j = 0; j < nCh; j += 64) {
    const int c = j + lane;
    unsigned int v = (c < nCh) ? row[c] : 0;
    unsigned int s = v;
    #pragma unroll
    for (int off = 1; off < 64; off <<= 1) {
      unsigned int t = __shfl_up(s, off, 64);
      if (lane >= off) s += t;
    }
    if (c < nCh) row[c] = running + s - v;       // exclusive within bucket
    running += __shfl(s, 63, 64);
  }
  if (lane == 0) tot[b] = running;
}

// ---------------------------------------------------------------------------
// K2c: one tiny block: exclusive scan of bucket totals -> bucket_base.
// ---------------------------------------------------------------------------
__global__ __launch_bounds__(256) void k_bscan2(
    const unsigned int* __restrict__ tot, int* __restrict__ bucket_base,
    int nB, int E)
{
  __shared__ unsigned int part[256];
  const int t = threadIdx.x;
  const unsigned int v = (t < nB) ? tot[t] : 0;
  part[t] = v;
  __syncthreads();
  for (int off = 1; off < 256; off <<= 1) {
    unsigned int u = (t >= off) ? part[t - off] : 0;
    __syncthreads();
    part[t] += u;
    __syncthreads();
  }
  if (t < nB) bucket_base[t] = (int)(part[t] - v);
  if (t == 0) bucket_base[nB] = E;
}

// ---------------------------------------------------------------------------
// K2d: bucket scatter with LDS staging -> COALESCED global dumps.
// Pack val = (src<<16)|dst. bucket(val) = val >> 24.
// gbase = bucket_base[b] + hist[b][chunk] (chunk-local exclusive base).
// ---------------------------------------------------------------------------
__global__ __launch_bounds__(1024) void k_b2(
    const int* __restrict__ src, const int* __restrict__ dst,
    const unsigned int* __restrict__ hist, const int* __restrict__ bucket_base,
    unsigned int* __restrict__ bucketed, int E, int nB, int nCh, int chunkLg)
{
  __shared__ unsigned int staged[8192];    // 32 KB (chunkLg=13)
  __shared__ unsigned int gbase[256];
  __shared__ unsigned int lhist[256];
  __shared__ unsigned int lbase[256];
  __shared__ unsigned int lcur[256];
  __shared__ unsigned int part[256];

  const int tid = threadIdx.x;
  const int c = blockIdx.x;
  if (tid < 256) lhist[tid] = 0;
  if (tid < nB)
    gbase[tid] = (unsigned int)bucket_base[tid] + hist[(size_t)tid * nCh + c];
  __syncthreads();

  const int e0 = c << chunkLg;
  const int e1 = min(e0 + (1 << chunkLg), E);
  const int csize = e1 - e0;

  for (int e = e0 + tid; e < e1; e += 1024)
    atomicAdd(&lhist[src[e] >> 8], 1u);
  __syncthreads();

  if (tid < 256) part[tid] = lhist[tid];
  __syncthreads();
  for (int off = 1; off < 256; off <<= 1) {
    unsigned int t = (tid < 256 && tid >= off) ? part[tid - off] : 0;
    __syncthreads();
    if (tid < 256) part[tid] += t;
    __syncthreads();
  }
  if (tid < 256) {
    lbase[tid] = part[tid] - lhist[tid];
    lcur[tid] = lbase[tid];
  }
  __syncthreads();

  for (int e = e0 + tid; e < e1; e += 1024) {
    const unsigned int s = (unsigned int)src[e];
    const unsigned int pos = atomicAdd(&lcur[s >> 8], 1u);
    staged[pos] = (s << 16) | (unsigned int)dst[e];
  }
  __syncthreads();

  // linear dump: consecutive i within a bucket run -> consecutive gpos
  for (int i = tid; i < csize; i += 1024) {
    const unsigned int v = staged[i];
    const unsigned int b = v >> 24;
    bucketed[gbase[b] + ((unsigned int)i - lbase[b])] = v;
  }
}

// ---------------------------------------------------------------------------
// K2e: one block per bucket: node hist + scan -> rowptr; scatter dst into
// LDS staging; contiguous coalesced dump into csr_dst.
// ---------------------------------------------------------------------------
__global__ __launch_bounds__(1024) void k_b3(
    const unsigned int* __restrict__ bucketed, const int* __restrict__ bucket_base,
    int* __restrict__ rowptr, unsigned short* __restrict__ csr_dst,
    int nB, int N, int E)
{
  __shared__ unsigned short staged[16384];   // 32 KB
  __shared__ unsigned int lh[256];
  __shared__ unsigned int part[256];
  __shared__ unsigned int cur[256];

  const int b = blockIdx.x;
  const int tid = threadIdx.x;
  const int seg0 = bucket_base[b];
  const int seg1 = bucket_base[b + 1];
  const int len = seg1 - seg0;
  if (tid < 256) lh[tid] = 0;
  __syncthreads();

  for (int j = seg0 + tid; j < seg1; j += 1024)
    atomicAdd(&lh[(bucketed[j] >> 16) & 0xFFu], 1u);
  __syncthreads();

  if (tid < 256) part[tid] = lh[tid];
  __syncthreads();
  for (int off = 1; off < 256; off <<= 1) {
    unsigned int t = (tid < 256 && tid >= off) ? part[tid - off] : 0;
    __syncthreads();
    if (tid < 256) part[tid] += t;
    __syncthreads();
  }
  if (tid < 256) {
    const unsigned int base = part[tid] - lh[tid];   // local exclusive
    cur[tid] = base;
    const int n = b * 256 + tid;
    if (n < N) rowptr[n] = seg0 + (int)base;
  }
  if (b == nB - 1 && tid == 0) rowptr[N] = E;
  __syncthreads();

  if (len <= 16384) {
    for (int j = seg0 + tid; j < seg1; j += 1024) {
      const unsigned int v = bucketed[j];
      const unsigned int pos = atomicAdd(&cur[(v >> 16) & 0xFFu], 1u);
      staged[pos] = (unsigned short)(v & 0xFFFFu);
    }
    __syncthreads();
    for (int i = tid; i < len; i += 1024)     // contiguous coalesced dump
      csr_dst[seg0 + i] = staged[i];
  } else {
    for (int j = seg0 + tid; j < seg1; j += 1024) {   // fallback
      const unsigned int v = bucketed[j];
      const unsigned int pos = atomicAdd(&cur[(v >> 16) & 0xFFu], 1u);
      csr_dst[seg0 + pos] = (unsigned short)(v & 0xFFFFu);
    }
  }
}

// ---------------------------------------------------------------------------
// K5: node-centric accumulate; wave/node; 2 edges per gather.
// h/dl broadcast through LDS; manual 4x batching for MLP.
// ---------------------------------------------------------------------------
__global__ __launch_bounds__(256) void k_node(
    const unsigned short* __restrict__ csr_dst, const int* __restrict__ rowptr,
    const float* __restrict__ s1, const float* __restrict__ s2,
    const float* __restrict__ ab, const unsigned short* __restrict__ zb,
    float* __restrict__ out, float* __restrict__ rinv, int N)
{
  __shared__ float hbuf[4][64];
  __shared__ int   dbuf[4][64];

  const int wave = threadIdx.x >> 6;
  const int node = blockIdx.x * 4 + wave;
  const int lane = threadIdx.x & 63;
  if (node >= N) return;
  const int r0 = rowptr[node];
  const int r1 = rowptr[node + 1];
  if (r1 == r0) {            // degree-0: reference yields zeros
    out[(size_t)node * HDIM + lane] = 0.f;
    if (lane == 0) rinv[node] = 0.f;
    return;
  }
  const float s1n = s1[node];
  const float b = ab[0];
  const int half = lane >> 5;
  const int fp = (lane & 31) << 1;   // feature pair base
  float ax = 0.f, ay = 0.f, hs = 0.f;
  float* hb = hbuf[wave];
  int*   db = dbuf[wave];

  for (int base = r0; base < r1; base += 64) {
    const int j = base + lane;
    float h = 0.f;
    int dl = 0;
    if (j < r1) {
      dl = (int)csr_dst[j];                  // coalesced u16
      float v = s1n + s2[dl] + b;            // gathered 4B (L2-resident)
      v = v > 0.f ? v : LEAKY * v;
      h = __expf(v);
    }
    hs += h;
    hb[lane] = h;                            // wave-private LDS, no barrier
    db[lane] = dl;
    const int cnt = min(64, r1 - base);
    const int pairs = (cnt + 1) >> 1;
    int t = 0;
    for (; t + 4 <= pairs; t += 4) {
      const int i0 = 2 * t + half;
      const float h0 = hb[i0],     h1 = hb[i0 + 2];
      const float h2 = hb[i0 + 4], h3 = hb[i0 + 6];
      const int   d0 = db[i0],     d1 = db[i0 + 2];
      const int   d2 = db[i0 + 4], d3 = db[i0 + 6];
      const unsigned int w0 = *reinterpret_cast<const unsigned int*>(zb + (size_t)d0 * HDIM + fp);
      const unsigned int w1 = *reinterpret_cast<const unsigned int*>(zb + (size_t)d1 * HDIM + fp);
      const unsigned int w2 = *reinterpret_cast<const unsigned int*>(zb + (size_t)d2 * HDIM + fp);
      const unsigned int w3 = *reinterpret_cast<const unsigned int*>(zb + (size_t)d3 * HDIM + fp);
      ax = fmaf(h0, __uint_as_float(w0 << 16), ax);
      ay = fmaf(h0, __uint_as_float(w0 & 0xffff0000u), ay);
      ax = fmaf(h1, __uint_as_float(w1 << 16), ax);
      ay = fmaf(h1, __uint_as_float(w1 & 0xffff0000u), ay);
      ax = fmaf(h2, __uint_as_float(w2 << 16), ax);
      ay = fmaf(h2, __uint_as_float(w2 & 0xffff0000u), ay);
      ax = fmaf(h3, __uint_as_float(w3 << 16), ax);
      ay = fmaf(h3, __uint_as_float(w3 & 0xffff0000u), ay);
    }
    for (; t < pairs; ++t) {
      const int i0 = 2 * t + half;
      const float hB = hb[i0];
      const int   dB = db[i0];
      const unsigned int w = *reinterpret_cast<const unsigned int*>(zb + (size_t)dB * HDIM + fp);
      ax = fmaf(hB, __uint_as_float(w << 16), ax);
      ay = fmaf(hB, __uint_as_float(w & 0xffff0000u), ay);
    }
  }
  #pragma unroll
  for (int off = 32; off > 0; off >>= 1) hs += __shfl_xor(hs, off, 64);
  // combine even/odd halves (same feature pair lives at lane^32)
  ax += __shfl_xor(ax, 32, 64);
  ay += __shfl_xor(ay, 32, 64);
  const float inv = 1.0f / hs;
  if (lane < 32) {
    float2 o = {ax * inv, ay * inv};
    *reinterpret_cast<float2*>(out + (size_t)node * HDIM + fp) = o;
    if (lane == 0) rinv[node] = inv;
  }
}

// ---------------------------------------------------------------------------
// K6: alpha in edge order (coalesced writes)
// ---------------------------------------------------------------------------
__global__ __launch_bounds__(256) void k_alpha(
    const int* __restrict__ src, const int* __restrict__ dst,
    const float* __restrict__ s1, const float* __restrict__ s2,
    const float* __restrict__ ab, const float* __restrict__ rinv,
    float* __restrict__ alpha, int E)
{
  int e = blockIdx.x * blockDim.x + threadIdx.x;
  if (e >= E) return;
  const int s = src[e];
  float v = s1[s] + s2[dst[e]] + ab[0];
  v = v > 0.f ? v : LEAKY * v;
  alpha[e] = __expf(v) * rinv[s];
}

extern "C" void kernel_launch(void* const* d_in, const int* in_sizes, int n_in,
                              void* d_out, int out_size, void* d_ws, size_t ws_size,
                              hipStream_t stream) {
  const int E  = in_sizes[1] / 2;
  const int H2 = in_sizes[3];            // 2*H = 128
  const int Hh = H2 / 2;                 // 64
  const int Ff = in_sizes[2] / Hh;       // 256
  const int N  = in_sizes[0] / Ff;       // 50000

  const float* x   = (const float*)d_in[0];
  const int*   ei  = (const int*)d_in[1];
  const float* fcw = (const float*)d_in[2];
  const float* aw  = (const float*)d_in[3];
  const float* ab  = (const float*)d_in[4];
  const int* src = ei;
  const int* dst = ei + E;

  float* out   = (float*)d_out;
  float* alpha = out + (size_t)N * HDIM;

  const int nB = (N + 255) >> 8;                      // node buckets (<=256)
  int chunkLg = 13;                                   // keep nCh <= 256
  while (((E + (1 << chunkLg) - 1) >> chunkLg) > 256) ++chunkLg;
  const int nCh = (E + (1 << chunkLg) - 1) >> chunkLg;

  // workspace layout:
  // zb u16[N*64] | s1 f32[N] | s2 f32[N] | rinv f32[N] | wb s16[16384]
  // | rowptr i32[N+1] | bucket_base i32[nB+2] | tot u32[256]
  // | bucketed u32[E] | hist u32[nB*nCh] | csr_dst u16[E]
  unsigned short* zb = (unsigned short*)d_ws;
  float* s1   = (float*)(zb + (size_t)N * HDIM);
  float* s2   = s1 + N;
  float* rinv = s2 + N;
  short* wb   = (short*)(rinv + N);
  int* rowptr = (int*)(wb + 8 * 4 * 64 * 8);
  int* bucket_base = rowptr + (N + 1);
  unsigned int* tot = (unsigned int*)(bucket_base + (nB + 2));
  unsigned int* bucketed = tot + 256;
  unsigned int* hist = bucketed + E;
  unsigned short* csr_dst = (unsigned short*)(hist + (size_t)nB * nCh);

  k_wt<<<8, 256, 0, stream>>>(fcw, wb);
  k_fcm<<<(N + 127) / 128, 256, 0, stream>>>(x, wb, aw, zb, s1, s2, N);

  k_b1<<<nCh, 1024, 0, stream>>>(src, hist, E, nB, nCh, chunkLg);
  k_bsum<<<(nB + 3) / 4, 256, 0, stream>>>(hist, tot, nB, nCh);
  k_bscan2<<<1, 256, 0, stream>>>(tot, bucket_base, nB, E);
  k_b2<<<nCh, 1024, 0, stream>>>(src, dst, hist, bucket_base, bucketed,
                                 E, nB, nCh, chunkLg);
  k_b3<<<nB, 1024, 0, stream>>>(bucketed, bucket_base, rowptr, csr_dst, nB, N, E);

  k_node<<<(N + 3) / 4, 256, 0, stream>>>(
      csr_dst, rowptr, s1, s2, ab, zb, out, rinv, N);

  const int eb = (E + 255) / 256;
  k_alpha<<<eb, 256, 0, stream>>>(src, dst, s1, s2, ab, rinv, alpha, E);
}